// Round 1
// baseline (866.869 us; speedup 1.0000x reference)
//
#include <hip/hip_runtime.h>
#include <hip/hip_bf16.h>
#include <cstdint>

#define NE   8
#define TOPK 2
#define NT   8192          // tokens
#define TK   16384         // tokens * topk
#define HS   1024
#define FFN  4096
#define CAP  2048          // expert capacity

typedef float  f32x4  __attribute__((ext_vector_type(4)));
typedef __bf16 bf16x8 __attribute__((ext_vector_type(8)));
typedef __bf16 bf16x4 __attribute__((ext_vector_type(4)));

// ---------------- async global->LDS (16B per lane) ----------------
__device__ __forceinline__ void gload_lds16(const void* g, void* l) {
  __builtin_amdgcn_global_load_lds(
      (__attribute__((address_space(1))) void*)(void*)g,
      (__attribute__((address_space(3))) void*)l,
      16, 0, 0);
}

// ---------------- routing: stable counting sort ranks ----------------
// 8 blocks (one per expert), 256 threads. For each assignment i (0..TK):
// p = #(j<i with te[j]==te[i]); valid = p < CAP.
__global__ void route_kernel(const int* __restrict__ te,
                             const float* __restrict__ ew,
                             int* __restrict__ asg_p,
                             float* __restrict__ asg_w,
                             int* __restrict__ slot_token) {
  const int e    = blockIdx.x;
  const int tid  = threadIdx.x;
  const int lane = tid & 63;
  const int w    = tid >> 6;
  __shared__ int wtot[4];
  int running = 0;
  for (int base = 0; base < TK; base += 256) {
    const int i = base + tid;
    const int flag = (te[i] == e) ? 1 : 0;
    int val = flag;                       // inclusive wave scan
    #pragma unroll
    for (int off = 1; off < 64; off <<= 1) {
      int n = __shfl_up(val, off);
      if (lane >= off) val += n;
    }
    if (lane == 63) wtot[w] = val;
    __syncthreads();
    int woff = 0;
    #pragma unroll
    for (int j = 0; j < 4; j++) if (j < w) woff += wtot[j];
    const int total = wtot[0] + wtot[1] + wtot[2] + wtot[3];
    if (flag) {
      const int p = running + woff + val - 1;   // exclusive rank
      asg_p[i] = p;
      const bool valid = (p < CAP);
      asg_w[i] = valid ? ew[i] : 0.0f;
      if (valid) slot_token[e * CAP + p] = i >> 1;  // i / TOPK
    }
    running += total;
    __syncthreads();
  }
}

// ---------------- gather + cast to bf16 ----------------
// grid = E*CAP blocks x 256 thr; each block one slot row (HS elems)
__global__ void gather_kernel(const float* __restrict__ x,
                              const int* __restrict__ slot_token,
                              __bf16* __restrict__ Xg) {
  const int s   = blockIdx.x;
  const int tok = slot_token[s];
  const int idx = threadIdx.x * 4;
  bf16x4 o;
  if (tok >= 0) {
    const float4 v = *(const float4*)&x[(size_t)tok * HS + idx];
    o[0] = (__bf16)v.x; o[1] = (__bf16)v.y; o[2] = (__bf16)v.z; o[3] = (__bf16)v.w;
  } else {
    o[0] = (__bf16)0.f; o[1] = (__bf16)0.f; o[2] = (__bf16)0.f; o[3] = (__bf16)0.f;
  }
  *(bf16x4*)&Xg[(size_t)s * HS + idx] = o;
}

// ---------------- transpose + cast: [R][C] f32 -> [C][R] bf16 per expert ----
// grid (C/64, R/64, NE), 256 thr, 64x64 tile in LDS (pad 65)
template<int R, int C>
__global__ void transpose_cast_kernel(const float* __restrict__ in,
                                      __bf16* __restrict__ out) {
  const int e = blockIdx.z;
  const float* in_e  = in  + (size_t)e * R * C;
  __bf16*      out_e = out + (size_t)e * R * C;
  const int c0 = blockIdx.x * 64;
  const int r0 = blockIdx.y * 64;
  __shared__ float tile[64][65];
  const int tid = threadIdx.x;
  const int lc = tid & 15, tr = tid >> 4;
  #pragma unroll
  for (int rr = 0; rr < 4; rr++) {
    const int row = rr * 16 + tr;
    const float4 v = *(const float4*)&in_e[(size_t)(r0 + row) * C + c0 + lc * 4];
    tile[row][lc * 4 + 0] = v.x; tile[row][lc * 4 + 1] = v.y;
    tile[row][lc * 4 + 2] = v.z; tile[row][lc * 4 + 3] = v.w;
  }
  __syncthreads();
  #pragma unroll
  for (int rr = 0; rr < 4; rr++) {
    const int orow = rr * 16 + tr;     // index along C
    bf16x4 o;
    o[0] = (__bf16)tile[lc * 4 + 0][orow];
    o[1] = (__bf16)tile[lc * 4 + 1][orow];
    o[2] = (__bf16)tile[lc * 4 + 2][orow];
    o[3] = (__bf16)tile[lc * 4 + 3][orow];
    *(bf16x4*)&out_e[(size_t)(c0 + orow) * R + r0 + lc * 4] = o;
  }
}

// ---------------- gelu (tanh approx, matches jax.nn.gelu) ----------------
__device__ __forceinline__ float gelu_tanh(float v) {
  const float u = 0.7978845608028654f * (v + 0.044715f * v * v * v);
  const float t = 1.0f - 2.0f / (__expf(2.0f * u) + 1.0f);
  return 0.5f * v * (1.0f + t);
}

// ---------------- grouped GEMM, m97 structure ----------------
// A: [NE*CAP][K] bf16 row-major (expert-contiguous rows)
// B: [NE][N][K] bf16 row-major (i.e. B^T per expert)
// C: [NE*CAP][N] bf16
// 128x128 tile, BK=32, 256 thr (4 waves, 2x2 of 64x64 wave tiles)
template<int DO_GELU>
__global__ __launch_bounds__(256)
void gemm_bt_kernel(const __bf16* __restrict__ A,
                    const __bf16* __restrict__ B,
                    __bf16* __restrict__ C,
                    int N, int K) {
  const int e  = blockIdx.z;
  const int m0 = blockIdx.x * 128;
  const int n0 = blockIdx.y * 128;
  const int tid  = threadIdx.x;
  const int lane = tid & 63;
  const int w    = tid >> 6;
  const int wm   = w & 1;
  const int wn   = w >> 1;

  __shared__ __bf16 lds_a[128 * 32];
  __shared__ __bf16 lds_b[128 * 32];

  const size_t Abase = ((size_t)e * CAP + m0) * K;
  const size_t Bbase = (size_t)e * N * K + (size_t)n0 * K;

  // staging: wave w stages rows [w*32, w*32+32) of each tile, 2 issues of 16 rows
  const int srow = w * 32 + (lane >> 2);
  const int scol = (lane & 3) * 8;
  const __bf16* gA = A + Abase + (size_t)srow * K + scol;
  const __bf16* gB = B + Bbase + (size_t)srow * K + scol;
  __bf16* la1 = &lds_a[(w * 32) * 32];
  __bf16* la2 = &lds_a[(w * 32 + 16) * 32];
  __bf16* lb1 = &lds_b[(w * 32) * 32];
  __bf16* lb2 = &lds_b[(w * 32 + 16) * 32];

  const int a_off = (wm * 64 + (lane & 15)) * 32 + (lane >> 4) * 8;
  const int b_off = (wn * 64 + (lane & 15)) * 32 + (lane >> 4) * 8;

  f32x4 acc[4][4] = {};

  for (int kk = 0; kk < K; kk += 32) {
    gload_lds16(gA + kk, la1);
    gload_lds16(gA + kk + (size_t)16 * K, la2);
    gload_lds16(gB + kk, lb1);
    gload_lds16(gB + kk + (size_t)16 * K, lb2);
    __syncthreads();

    bf16x8 af[4], bf[4];
    #pragma unroll
    for (int mt = 0; mt < 4; mt++) af[mt] = *(const bf16x8*)&lds_a[a_off + mt * 512];
    #pragma unroll
    for (int nt = 0; nt < 4; nt++) bf[nt] = *(const bf16x8*)&lds_b[b_off + nt * 512];
    #pragma unroll
    for (int mt = 0; mt < 4; mt++)
      #pragma unroll
      for (int nt = 0; nt < 4; nt++)
        acc[mt][nt] = __builtin_amdgcn_mfma_f32_16x16x32_bf16(af[mt], bf[nt], acc[mt][nt], 0, 0, 0);
    __syncthreads();
  }

  // epilogue: D row=(lane>>4)*4+r (m), col=lane&15 (n)
  const int crow = (lane >> 4) * 4;
  const int ccol = lane & 15;
  const size_t Crow0 = (size_t)e * CAP + m0;
  #pragma unroll
  for (int mt = 0; mt < 4; mt++) {
    #pragma unroll
    for (int nt = 0; nt < 4; nt++) {
      const f32x4 d = acc[mt][nt];
      const int col = n0 + wn * 64 + nt * 16 + ccol;
      #pragma unroll
      for (int r = 0; r < 4; r++) {
        float v = d[r];
        if (DO_GELU) v = gelu_tanh(v);
        const size_t row = Crow0 + wm * 64 + mt * 16 + crow + r;
        C[row * N + col] = (__bf16)v;
      }
    }
  }
}

// ---------------- combine: y = bias + sum_k w * Out[slot] ----------------
// grid = NT blocks x 256 thr
__global__ void combine_kernel(const __bf16* __restrict__ Out,
                               const int* __restrict__ te,
                               const int* __restrict__ asg_p,
                               const float* __restrict__ asg_w,
                               const float* __restrict__ bias,
                               float* __restrict__ y) {
  const int t   = blockIdx.x;
  const int idx = threadIdx.x * 4;
  f32x4 acc = *(const f32x4*)&bias[idx];
  #pragma unroll
  for (int j = 0; j < TOPK; j++) {
    const int i = t * TOPK + j;
    const float wgt = asg_w[i];
    if (wgt != 0.0f) {
      const int slot = te[i] * CAP + asg_p[i];
      const bf16x4 o = *(const bf16x4*)&Out[(size_t)slot * HS + idx];
      acc[0] += wgt * (float)o[0];
      acc[1] += wgt * (float)o[1];
      acc[2] += wgt * (float)o[2];
      acc[3] += wgt * (float)o[3];
    }
  }
  *(f32x4*)&y[(size_t)t * HS + idx] = acc;
}

// ---------------- workspace layout (bytes) ----------------
static constexpr size_t OFF_SLOT = 0;                          //  64 KB int
static constexpr size_t OFF_ASGP = 65536;                      //  64 KB int
static constexpr size_t OFF_ASGW = 131072;                     //  64 KB f32
static constexpr size_t OFF_XG   = 196608;                     //  32 MB bf16 [NE*CAP][HS]
static constexpr size_t OFF_W1T  = OFF_XG  + (size_t)TK * HS * 2;        // 64 MB bf16 [NE][FFN][HS]
static constexpr size_t OFF_W2T  = OFF_W1T + (size_t)NE * HS * FFN * 2;  // 64 MB bf16 [NE][HS][FFN]
static constexpr size_t OFF_H    = OFF_W2T + (size_t)NE * HS * FFN * 2;  // 128 MB bf16 [NE*CAP][FFN]
static constexpr size_t OFF_OUT  = OFF_H   + (size_t)NE * CAP * FFN * 2; // 32 MB bf16 [NE*CAP][HS]

extern "C" void kernel_launch(void* const* d_in, const int* in_sizes, int n_in,
                              void* d_out, int out_size, void* d_ws, size_t ws_size,
                              hipStream_t stream) {
  const float* x    = (const float*)d_in[0];
  const float* ew   = (const float*)d_in[1];
  const float* w1   = (const float*)d_in[2];
  const float* w2   = (const float*)d_in[3];
  const float* bias = (const float*)d_in[4];
  const int*   te   = (const int*)d_in[5];
  float* y = (float*)d_out;

  char* ws = (char*)d_ws;
  int*    slot_token = (int*)(ws + OFF_SLOT);
  int*    asg_p      = (int*)(ws + OFF_ASGP);
  float*  asg_w      = (float*)(ws + OFF_ASGW);
  __bf16* Xg         = (__bf16*)(ws + OFF_XG);
  __bf16* W1t        = (__bf16*)(ws + OFF_W1T);
  __bf16* W2t        = (__bf16*)(ws + OFF_W2T);
  __bf16* H          = (__bf16*)(ws + OFF_H);
  __bf16* Out        = (__bf16*)(ws + OFF_OUT);

  // 1. slot_token = -1
  hipMemsetAsync(slot_token, 0xFF, (size_t)NE * CAP * sizeof(int), stream);

  // 2. routing (stable ranks)
  route_kernel<<<NE, 256, 0, stream>>>(te, ew, asg_p, asg_w, slot_token);

  // 3. weight transpose+cast  (w1: [HS][FFN] -> [FFN][HS];  w2: [FFN][HS] -> [HS][FFN])
  transpose_cast_kernel<HS, FFN><<<dim3(FFN / 64, HS / 64, NE), 256, 0, stream>>>(w1, W1t);
  transpose_cast_kernel<FFN, HS><<<dim3(HS / 64, FFN / 64, NE), 256, 0, stream>>>(w2, W2t);

  // 4. gather tokens into expert bins (bf16)
  gather_kernel<<<NE * CAP, 256, 0, stream>>>(x, slot_token, Xg);

  // 5. H = gelu(Xg @ w1)   (M=CAP per expert, N=FFN, K=HS)
  gemm_bt_kernel<1><<<dim3(CAP / 128, FFN / 128, NE), 256, 0, stream>>>(Xg, W1t, H, FFN, HS);

  // 6. Out = H @ w2        (M=CAP per expert, N=HS, K=FFN)
  gemm_bt_kernel<0><<<dim3(CAP / 128, HS / 128, NE), 256, 0, stream>>>(H, W2t, Out, HS, FFN);

  // 7. combine back to tokens
  combine_kernel<<<NT, 256, 0, stream>>>(Out, te, asg_p, asg_w, bias, y);
}

// Round 2
// 850.828 us; speedup vs baseline: 1.0189x; 1.0189x over previous
//
#include <hip/hip_runtime.h>
#include <hip/hip_bf16.h>
#include <cstdint>

#define NE   8
#define TOPK 2
#define NT   8192          // tokens
#define TK   16384         // tokens * topk
#define HS   1024
#define FFN  4096
#define CAP  2048          // expert capacity

typedef float  f32x4  __attribute__((ext_vector_type(4)));
typedef __bf16 bf16x8 __attribute__((ext_vector_type(8)));
typedef __bf16 bf16x4 __attribute__((ext_vector_type(4)));

// ---------------- async global->LDS (16B per lane) ----------------
__device__ __forceinline__ void gload_lds16(const void* g, void* l) {
  __builtin_amdgcn_global_load_lds(
      (__attribute__((address_space(1))) void*)(void*)g,
      (__attribute__((address_space(3))) void*)l,
      16, 0, 0);
}

// ---------------- routing: stable counting sort ranks ----------------
__global__ void route_kernel(const int* __restrict__ te,
                             const float* __restrict__ ew,
                             int* __restrict__ asg_p,
                             float* __restrict__ asg_w,
                             int* __restrict__ slot_token) {
  const int e    = blockIdx.x;
  const int tid  = threadIdx.x;
  const int lane = tid & 63;
  const int w    = tid >> 6;
  __shared__ int wtot[4];
  int running = 0;
  for (int base = 0; base < TK; base += 256) {
    const int i = base + tid;
    const int flag = (te[i] == e) ? 1 : 0;
    int val = flag;                       // inclusive wave scan
    #pragma unroll
    for (int off = 1; off < 64; off <<= 1) {
      int n = __shfl_up(val, off);
      if (lane >= off) val += n;
    }
    if (lane == 63) wtot[w] = val;
    __syncthreads();
    int woff = 0;
    #pragma unroll
    for (int j = 0; j < 4; j++) if (j < w) woff += wtot[j];
    const int total = wtot[0] + wtot[1] + wtot[2] + wtot[3];
    if (flag) {
      const int p = running + woff + val - 1;   // exclusive rank
      asg_p[i] = p;
      const bool valid = (p < CAP);
      asg_w[i] = valid ? ew[i] : 0.0f;
      if (valid) slot_token[e * CAP + p] = i >> 1;  // i / TOPK
    }
    running += total;
    __syncthreads();
  }
}

// ---------------- gather + cast to bf16 ----------------
__global__ void gather_kernel(const float* __restrict__ x,
                              const int* __restrict__ slot_token,
                              __bf16* __restrict__ Xg) {
  const int s   = blockIdx.x;
  const int tok = slot_token[s];
  const int idx = threadIdx.x * 4;
  bf16x4 o;
  if (tok >= 0) {
    const float4 v = *(const float4*)&x[(size_t)tok * HS + idx];
    o[0] = (__bf16)v.x; o[1] = (__bf16)v.y; o[2] = (__bf16)v.z; o[3] = (__bf16)v.w;
  } else {
    o[0] = (__bf16)0.f; o[1] = (__bf16)0.f; o[2] = (__bf16)0.f; o[3] = (__bf16)0.f;
  }
  *(bf16x4*)&Xg[(size_t)s * HS + idx] = o;
}

// ---------------- transpose + cast: [R][C] f32 -> [C][R] bf16 per expert ----
template<int R, int C>
__global__ void transpose_cast_kernel(const float* __restrict__ in,
                                      __bf16* __restrict__ out) {
  const int e = blockIdx.z;
  const float* in_e  = in  + (size_t)e * R * C;
  __bf16*      out_e = out + (size_t)e * R * C;
  const int c0 = blockIdx.x * 64;
  const int r0 = blockIdx.y * 64;
  __shared__ float tile[64][65];
  const int tid = threadIdx.x;
  const int lc = tid & 15, tr = tid >> 4;
  #pragma unroll
  for (int rr = 0; rr < 4; rr++) {
    const int row = rr * 16 + tr;
    const float4 v = *(const float4*)&in_e[(size_t)(r0 + row) * C + c0 + lc * 4];
    tile[row][lc * 4 + 0] = v.x; tile[row][lc * 4 + 1] = v.y;
    tile[row][lc * 4 + 2] = v.z; tile[row][lc * 4 + 3] = v.w;
  }
  __syncthreads();
  #pragma unroll
  for (int rr = 0; rr < 4; rr++) {
    const int orow = rr * 16 + tr;     // index along C
    bf16x4 o;
    o[0] = (__bf16)tile[lc * 4 + 0][orow];
    o[1] = (__bf16)tile[lc * 4 + 1][orow];
    o[2] = (__bf16)tile[lc * 4 + 2][orow];
    o[3] = (__bf16)tile[lc * 4 + 3][orow];
    *(bf16x4*)&out_e[(size_t)(c0 + orow) * R + r0 + lc * 4] = o;
  }
}

// ---------------- gelu (tanh approx, matches jax.nn.gelu) ----------------
__device__ __forceinline__ float gelu_tanh(float v) {
  const float u = 0.7978845608028654f * (v + 0.044715f * v * v * v);
  const float t = 1.0f - 2.0f / (__expf(2.0f * u) + 1.0f);
  return 0.5f * v * (1.0f + t);
}

// ---------------- grouped GEMM, double-buffered LDS ----------------
// A: [NE*CAP][K] bf16 row-major, B: [NE][N][K] bf16 (B^T), C: [NE*CAP][N] bf16
// 128x128 tile, BK=32, 256 thr (4 waves, 2x2 of 64x64 wave tiles).
// Staging for tile k+1 is issued right AFTER the barrier, so the vmcnt(0)
// drain at the NEXT barrier finds those loads already complete (one full
// MFMA phase in flight). One barrier per K-iter.
template<int DO_GELU>
__global__ __launch_bounds__(256)
void gemm_bt_kernel(const __bf16* __restrict__ A,
                    const __bf16* __restrict__ B,
                    __bf16* __restrict__ C,
                    int N, int K) {
  const int e  = blockIdx.z;
  const int m0 = blockIdx.x * 128;
  const int n0 = blockIdx.y * 128;
  const int tid  = threadIdx.x;
  const int lane = tid & 63;
  const int w    = tid >> 6;
  const int wm   = w & 1;
  const int wn   = w >> 1;

  __shared__ __bf16 lds_a[2][128 * 32];
  __shared__ __bf16 lds_b[2][128 * 32];

  const size_t Abase = ((size_t)e * CAP + m0) * K;
  const size_t Bbase = (size_t)e * N * K + (size_t)n0 * K;

  // staging: wave w stages rows [w*32, w*32+32), 2 issues of 16 rows each
  const int srow = w * 32 + (lane >> 2);
  const int scol = (lane & 3) * 8;
  const __bf16* gA = A + Abase + (size_t)srow * K + scol;
  const __bf16* gB = B + Bbase + (size_t)srow * K + scol;
  const int l1 = (w * 32) * 32;        // elem offset of this wave's first 16 rows
  const int l2 = (w * 32 + 16) * 32;

  const int a_off = (wm * 64 + (lane & 15)) * 32 + (lane >> 4) * 8;
  const int b_off = (wn * 64 + (lane & 15)) * 32 + (lane >> 4) * 8;

  f32x4 acc[4][4] = {};

  // prologue: stage tile 0 into buffer 0
  gload_lds16(gA, &lds_a[0][l1]);
  gload_lds16(gA + (size_t)16 * K, &lds_a[0][l2]);
  gload_lds16(gB, &lds_b[0][l1]);
  gload_lds16(gB + (size_t)16 * K, &lds_b[0][l2]);

  int p = 0;
  for (int kk = 0; kk < K; kk += 32, p ^= 1) {
    __syncthreads();   // drains staging of buf p; orders prior reads of buf p^1
    const int kn = kk + 32;
    if (kn < K) {      // prefetch next tile into buf p^1 (drained only at NEXT barrier)
      gload_lds16(gA + kn, &lds_a[p ^ 1][l1]);
      gload_lds16(gA + kn + (size_t)16 * K, &lds_a[p ^ 1][l2]);
      gload_lds16(gB + kn, &lds_b[p ^ 1][l1]);
      gload_lds16(gB + kn + (size_t)16 * K, &lds_b[p ^ 1][l2]);
    }

    bf16x8 af[4], bf[4];
    #pragma unroll
    for (int mt = 0; mt < 4; mt++) af[mt] = *(const bf16x8*)&lds_a[p][a_off + mt * 512];
    #pragma unroll
    for (int nt = 0; nt < 4; nt++) bf[nt] = *(const bf16x8*)&lds_b[p][b_off + nt * 512];
    #pragma unroll
    for (int mt = 0; mt < 4; mt++)
      #pragma unroll
      for (int nt = 0; nt < 4; nt++)
        acc[mt][nt] = __builtin_amdgcn_mfma_f32_16x16x32_bf16(af[mt], bf[nt], acc[mt][nt], 0, 0, 0);
  }

  // epilogue: D row=(lane>>4)*4+r (m), col=lane&15 (n)
  const int crow = (lane >> 4) * 4;
  const int ccol = lane & 15;
  const size_t Crow0 = (size_t)e * CAP + m0;
  #pragma unroll
  for (int mt = 0; mt < 4; mt++) {
    #pragma unroll
    for (int nt = 0; nt < 4; nt++) {
      const f32x4 d = acc[mt][nt];
      const int col = n0 + wn * 64 + nt * 16 + ccol;
      #pragma unroll
      for (int r = 0; r < 4; r++) {
        float v = d[r];
        if (DO_GELU) v = gelu_tanh(v);
        const size_t row = Crow0 + wm * 64 + mt * 16 + crow + r;
        C[row * N + col] = (__bf16)v;
      }
    }
  }
}

// ---------------- combine: y = bias + sum_k w * Out[slot] ----------------
__global__ void combine_kernel(const __bf16* __restrict__ Out,
                               const int* __restrict__ te,
                               const int* __restrict__ asg_p,
                               const float* __restrict__ asg_w,
                               const float* __restrict__ bias,
                               float* __restrict__ y) {
  const int t   = blockIdx.x;
  const int idx = threadIdx.x * 4;
  f32x4 acc = *(const f32x4*)&bias[idx];
  #pragma unroll
  for (int j = 0; j < TOPK; j++) {
    const int i = t * TOPK + j;
    const float wgt = asg_w[i];
    if (wgt != 0.0f) {
      const int slot = te[i] * CAP + asg_p[i];
      const bf16x4 o = *(const bf16x4*)&Out[(size_t)slot * HS + idx];
      acc[0] += wgt * (float)o[0];
      acc[1] += wgt * (float)o[1];
      acc[2] += wgt * (float)o[2];
      acc[3] += wgt * (float)o[3];
    }
  }
  *(f32x4*)&y[(size_t)t * HS + idx] = acc;
}

// ---------------- workspace layout (bytes) ----------------
static constexpr size_t OFF_SLOT = 0;                          //  64 KB int
static constexpr size_t OFF_ASGP = 65536;                      //  64 KB int
static constexpr size_t OFF_ASGW = 131072;                     //  64 KB f32
static constexpr size_t OFF_XG   = 196608;                     //  32 MB bf16 [NE*CAP][HS]
static constexpr size_t OFF_W1T  = OFF_XG  + (size_t)TK * HS * 2;        // 64 MB bf16 [NE][FFN][HS]
static constexpr size_t OFF_W2T  = OFF_W1T + (size_t)NE * HS * FFN * 2;  // 64 MB bf16 [NE][HS][FFN]
static constexpr size_t OFF_H    = OFF_W2T + (size_t)NE * HS * FFN * 2;  // 128 MB bf16 [NE*CAP][FFN]
static constexpr size_t OFF_OUT  = OFF_H   + (size_t)NE * CAP * FFN * 2; // 32 MB bf16 [NE*CAP][HS]

extern "C" void kernel_launch(void* const* d_in, const int* in_sizes, int n_in,
                              void* d_out, int out_size, void* d_ws, size_t ws_size,
                              hipStream_t stream) {
  const float* x    = (const float*)d_in[0];
  const float* ew   = (const float*)d_in[1];
  const float* w1   = (const float*)d_in[2];
  const float* w2   = (const float*)d_in[3];
  const float* bias = (const float*)d_in[4];
  const int*   te   = (const int*)d_in[5];
  float* y = (float*)d_out;

  char* ws = (char*)d_ws;
  int*    slot_token = (int*)(ws + OFF_SLOT);
  int*    asg_p      = (int*)(ws + OFF_ASGP);
  float*  asg_w      = (float*)(ws + OFF_ASGW);
  __bf16* Xg         = (__bf16*)(ws + OFF_XG);
  __bf16* W1t        = (__bf16*)(ws + OFF_W1T);
  __bf16* W2t        = (__bf16*)(ws + OFF_W2T);
  __bf16* H          = (__bf16*)(ws + OFF_H);
  __bf16* Out        = (__bf16*)(ws + OFF_OUT);

  // 1. slot_token = -1
  hipMemsetAsync(slot_token, 0xFF, (size_t)NE * CAP * sizeof(int), stream);

  // 2. routing (stable ranks)
  route_kernel<<<NE, 256, 0, stream>>>(te, ew, asg_p, asg_w, slot_token);

  // 3. weight transpose+cast  (w1: [HS][FFN] -> [FFN][HS];  w2: [FFN][HS] -> [HS][FFN])
  transpose_cast_kernel<HS, FFN><<<dim3(FFN / 64, HS / 64, NE), 256, 0, stream>>>(w1, W1t);
  transpose_cast_kernel<FFN, HS><<<dim3(HS / 64, FFN / 64, NE), 256, 0, stream>>>(w2, W2t);

  // 4. gather tokens into expert bins (bf16)
  gather_kernel<<<NE * CAP, 256, 0, stream>>>(x, slot_token, Xg);

  // 5. H = gelu(Xg @ w1)   (M=CAP per expert, N=FFN, K=HS)
  gemm_bt_kernel<1><<<dim3(CAP / 128, FFN / 128, NE), 256, 0, stream>>>(Xg, W1t, H, FFN, HS);

  // 6. Out = H @ w2        (M=CAP per expert, N=HS, K=FFN)
  gemm_bt_kernel<0><<<dim3(CAP / 128, HS / 128, NE), 256, 0, stream>>>(H, W2t, Out, HS, FFN);

  // 7. combine back to tokens
  combine_kernel<<<NT, 256, 0, stream>>>(Out, te, asg_p, asg_w, bias, y);
}

// Round 3
// 713.484 us; speedup vs baseline: 1.2150x; 1.1925x over previous
//
#include <hip/hip_runtime.h>
#include <hip/hip_bf16.h>
#include <cstdint>

#define NE   8
#define TOPK 2
#define NT   8192          // tokens
#define TK   16384         // tokens * topk
#define HS   1024
#define FFN  4096
#define CAP  2048          // expert capacity

typedef float  f32x4  __attribute__((ext_vector_type(4)));
typedef __bf16 bf16x8 __attribute__((ext_vector_type(8)));
typedef __bf16 bf16x4 __attribute__((ext_vector_type(4)));

// ---------------- async global->LDS (16B per lane) ----------------
__device__ __forceinline__ void gload_lds16(const void* g, void* l) {
  __builtin_amdgcn_global_load_lds(
      (__attribute__((address_space(1))) void*)(void*)g,
      (__attribute__((address_space(3))) void*)l,
      16, 0, 0);
}

// ---------------- routing: stable counting sort ranks ----------------
// 8 blocks (one per expert), 1024 threads (16 waves).
__global__ __launch_bounds__(1024)
void route_kernel(const int* __restrict__ te,
                  const float* __restrict__ ew,
                  int* __restrict__ asg_p,
                  float* __restrict__ asg_w,
                  int* __restrict__ slot_token) {
  const int e    = blockIdx.x;
  const int tid  = threadIdx.x;
  const int lane = tid & 63;
  const int w    = tid >> 6;
  __shared__ int wtot[16];
  int running = 0;
  for (int base = 0; base < TK; base += 1024) {
    const int i = base + tid;
    const int flag = (te[i] == e) ? 1 : 0;
    int val = flag;                       // inclusive wave scan
    #pragma unroll
    for (int off = 1; off < 64; off <<= 1) {
      int n = __shfl_up(val, off);
      if (lane >= off) val += n;
    }
    if (lane == 63) wtot[w] = val;
    __syncthreads();
    int woff = 0, total = 0;
    #pragma unroll
    for (int j = 0; j < 16; j++) {
      const int t = wtot[j];
      if (j < w) woff += t;
      total += t;
    }
    if (flag) {
      const int p = running + woff + val - 1;   // exclusive rank
      asg_p[i] = p;
      const bool valid = (p < CAP);
      asg_w[i] = valid ? ew[i] : 0.0f;
      if (valid) slot_token[e * CAP + p] = i >> 1;  // i / TOPK
    }
    running += total;
    __syncthreads();
  }
}

// ---------------- gather + cast to bf16 ----------------
__global__ void gather_kernel(const float* __restrict__ x,
                              const int* __restrict__ slot_token,
                              __bf16* __restrict__ Xg) {
  const int s   = blockIdx.x;
  const int tok = slot_token[s];
  const int idx = threadIdx.x * 4;
  bf16x4 o;
  if (tok >= 0) {
    const float4 v = *(const float4*)&x[(size_t)tok * HS + idx];
    o[0] = (__bf16)v.x; o[1] = (__bf16)v.y; o[2] = (__bf16)v.z; o[3] = (__bf16)v.w;
  } else {
    o[0] = (__bf16)0.f; o[1] = (__bf16)0.f; o[2] = (__bf16)0.f; o[3] = (__bf16)0.f;
  }
  *(bf16x4*)&Xg[(size_t)s * HS + idx] = o;
}

// ---------------- transpose + cast: [R][C] f32 -> [C][R] bf16 per expert ----
// 16-B coalesced loads AND stores; LDS 64x65 f32 tile.
template<int R, int C>
__global__ void transpose_cast_kernel(const float* __restrict__ in,
                                      __bf16* __restrict__ out) {
  const int e = blockIdx.z;
  const float* in_e  = in  + (size_t)e * R * C;
  __bf16*      out_e = out + (size_t)e * R * C;
  const int c0 = blockIdx.x * 64;
  const int r0 = blockIdx.y * 64;
  __shared__ float tile[64][65];
  const int tid = threadIdx.x;
  const int lc = tid & 15, tr = tid >> 4;
  #pragma unroll
  for (int rr = 0; rr < 4; rr++) {
    const int row = rr * 16 + tr;
    const float4 v = *(const float4*)&in_e[(size_t)(r0 + row) * C + c0 + lc * 4];
    tile[row][lc * 4 + 0] = v.x; tile[row][lc * 4 + 1] = v.y;
    tile[row][lc * 4 + 2] = v.z; tile[row][lc * 4 + 3] = v.w;
  }
  __syncthreads();
  // store: each thread writes 8 consecutive bf16 (16 B) along the output row
  const int cb = tid & 7;              // which 8-col group along R
  #pragma unroll
  for (int p = 0; p < 2; p++) {
    const int orow = p * 32 + (tid >> 3);     // index along C
    bf16x8 o;
    #pragma unroll
    for (int j = 0; j < 8; j++) o[j] = (__bf16)tile[cb * 8 + j][orow];
    *(bf16x8*)&out_e[(size_t)(c0 + orow) * R + r0 + cb * 8] = o;
  }
}

// ---------------- gelu (tanh approx, matches jax.nn.gelu) ----------------
__device__ __forceinline__ float gelu_tanh(float v) {
  const float u = 0.7978845608028654f * (v + 0.044715f * v * v * v);
  const float t = 1.0f - 2.0f / (__expf(2.0f * u) + 1.0f);
  return 0.5f * v * (1.0f + t);
}

// ---------------- grouped GEMM, double-buffered, XCD-swizzled ----------------
// A: [NE*CAP][K] bf16 row-major, B: [NE][N][K] bf16 (B^T), C: [NE*CAP][N] bf16
// 1-D grid; expert = bid % 8 (maps one expert per XCD under the usual
// round-robin linear->XCD assignment); within expert, 4x4 super-tiles so
// concurrently-resident blocks on one XCD share few A/B panels (L2 locality).
template<int DO_GELU, int MT, int NT_>
__global__ __launch_bounds__(256, 3)
void gemm_bt_kernel(const __bf16* __restrict__ A,
                    const __bf16* __restrict__ B,
                    __bf16* __restrict__ C,
                    int N, int K) {
  const int bid = blockIdx.x;
  const int e   = bid & 7;
  const int g   = bid >> 3;
  const int s   = g >> 4;           // super-tile id
  const int r   = g & 15;           // position in 4x4 super-tile
  const int sm  = s % (MT / 4);     // m-major super order
  const int sn  = s / (MT / 4);
  const int m0  = (sm * 4 + (r >> 2)) * 128;
  const int n0  = (sn * 4 + (r & 3)) * 128;

  const int tid  = threadIdx.x;
  const int lane = tid & 63;
  const int w    = tid >> 6;
  const int wm   = w & 1;
  const int wn   = w >> 1;

  __shared__ __bf16 lds_a[2][128 * 32];
  __shared__ __bf16 lds_b[2][128 * 32];

  const size_t Abase = ((size_t)e * CAP + m0) * K;
  const size_t Bbase = (size_t)e * N * K + (size_t)n0 * K;

  // staging: wave w stages rows [w*32, w*32+32), 2 issues of 16 rows each
  const int srow = w * 32 + (lane >> 2);
  const int scol = (lane & 3) * 8;
  const __bf16* gA = A + Abase + (size_t)srow * K + scol;
  const __bf16* gB = B + Bbase + (size_t)srow * K + scol;
  const int l1 = (w * 32) * 32;
  const int l2 = (w * 32 + 16) * 32;

  const int a_off = (wm * 64 + (lane & 15)) * 32 + (lane >> 4) * 8;
  const int b_off = (wn * 64 + (lane & 15)) * 32 + (lane >> 4) * 8;

  f32x4 acc[4][4] = {};

  // prologue: stage tile 0 into buffer 0
  gload_lds16(gA, &lds_a[0][l1]);
  gload_lds16(gA + (size_t)16 * K, &lds_a[0][l2]);
  gload_lds16(gB, &lds_b[0][l1]);
  gload_lds16(gB + (size_t)16 * K, &lds_b[0][l2]);

  int p = 0;
  for (int kk = 0; kk < K; kk += 32, p ^= 1) {
    __syncthreads();   // drains staging of buf p; orders prior reads of buf p^1
    const int kn = kk + 32;
    if (kn < K) {      // prefetch next tile into buf p^1
      gload_lds16(gA + kn, &lds_a[p ^ 1][l1]);
      gload_lds16(gA + kn + (size_t)16 * K, &lds_a[p ^ 1][l2]);
      gload_lds16(gB + kn, &lds_b[p ^ 1][l1]);
      gload_lds16(gB + kn + (size_t)16 * K, &lds_b[p ^ 1][l2]);
    }

    bf16x8 af[4], bf[4];
    #pragma unroll
    for (int mt = 0; mt < 4; mt++) af[mt] = *(const bf16x8*)&lds_a[p][a_off + mt * 512];
    #pragma unroll
    for (int nt = 0; nt < 4; nt++) bf[nt] = *(const bf16x8*)&lds_b[p][b_off + nt * 512];
    #pragma unroll
    for (int mt = 0; mt < 4; mt++)
      #pragma unroll
      for (int nt = 0; nt < 4; nt++)
        acc[mt][nt] = __builtin_amdgcn_mfma_f32_16x16x32_bf16(af[mt], bf[nt], acc[mt][nt], 0, 0, 0);
  }

  // epilogue: D row=(lane>>4)*4+r (m), col=lane&15 (n)
  const int crow = (lane >> 4) * 4;
  const int ccol = lane & 15;
  const size_t Crow0 = (size_t)e * CAP + m0;
  #pragma unroll
  for (int mt = 0; mt < 4; mt++) {
    #pragma unroll
    for (int nt = 0; nt < 4; nt++) {
      const f32x4 d = acc[mt][nt];
      const int col = n0 + wn * 64 + nt * 16 + ccol;
      #pragma unroll
      for (int rr = 0; rr < 4; rr++) {
        float v = d[rr];
        if (DO_GELU) v = gelu_tanh(v);
        const size_t row = Crow0 + wm * 64 + mt * 16 + crow + rr;
        C[row * N + col] = (__bf16)v;
      }
    }
  }
}

// ---------------- combine: y = bias + sum_k w * Out[slot] ----------------
__global__ void combine_kernel(const __bf16* __restrict__ Out,
                               const int* __restrict__ te,
                               const int* __restrict__ asg_p,
                               const float* __restrict__ asg_w,
                               const float* __restrict__ bias,
                               float* __restrict__ y) {
  const int t   = blockIdx.x;
  const int idx = threadIdx.x * 4;
  f32x4 acc = *(const f32x4*)&bias[idx];
  #pragma unroll
  for (int j = 0; j < TOPK; j++) {
    const int i = t * TOPK + j;
    const float wgt = asg_w[i];
    if (wgt != 0.0f) {
      const int slot = te[i] * CAP + asg_p[i];
      const bf16x4 o = *(const bf16x4*)&Out[(size_t)slot * HS + idx];
      acc[0] += wgt * (float)o[0];
      acc[1] += wgt * (float)o[1];
      acc[2] += wgt * (float)o[2];
      acc[3] += wgt * (float)o[3];
    }
  }
  *(f32x4*)&y[(size_t)t * HS + idx] = acc;
}

// ---------------- workspace layout (bytes) ----------------
static constexpr size_t OFF_SLOT = 0;                          //  64 KB int
static constexpr size_t OFF_ASGP = 65536;                      //  64 KB int
static constexpr size_t OFF_ASGW = 131072;                     //  64 KB f32
static constexpr size_t OFF_XG   = 196608;                     //  32 MB bf16 [NE*CAP][HS]
static constexpr size_t OFF_W1T  = OFF_XG  + (size_t)TK * HS * 2;        // 64 MB bf16 [NE][FFN][HS]
static constexpr size_t OFF_W2T  = OFF_W1T + (size_t)NE * HS * FFN * 2;  // 64 MB bf16 [NE][HS][FFN]
static constexpr size_t OFF_H    = OFF_W2T + (size_t)NE * HS * FFN * 2;  // 128 MB bf16 [NE*CAP][FFN]
static constexpr size_t OFF_OUT  = OFF_H   + (size_t)NE * CAP * FFN * 2; // 32 MB bf16 [NE*CAP][HS]

extern "C" void kernel_launch(void* const* d_in, const int* in_sizes, int n_in,
                              void* d_out, int out_size, void* d_ws, size_t ws_size,
                              hipStream_t stream) {
  const float* x    = (const float*)d_in[0];
  const float* ew   = (const float*)d_in[1];
  const float* w1   = (const float*)d_in[2];
  const float* w2   = (const float*)d_in[3];
  const float* bias = (const float*)d_in[4];
  const int*   te   = (const int*)d_in[5];
  float* y = (float*)d_out;

  char* ws = (char*)d_ws;
  int*    slot_token = (int*)(ws + OFF_SLOT);
  int*    asg_p      = (int*)(ws + OFF_ASGP);
  float*  asg_w      = (float*)(ws + OFF_ASGW);
  __bf16* Xg         = (__bf16*)(ws + OFF_XG);
  __bf16* W1t        = (__bf16*)(ws + OFF_W1T);
  __bf16* W2t        = (__bf16*)(ws + OFF_W2T);
  __bf16* H          = (__bf16*)(ws + OFF_H);
  __bf16* Out        = (__bf16*)(ws + OFF_OUT);

  // 1. slot_token = -1
  hipMemsetAsync(slot_token, 0xFF, (size_t)NE * CAP * sizeof(int), stream);

  // 2. routing (stable ranks)
  route_kernel<<<NE, 1024, 0, stream>>>(te, ew, asg_p, asg_w, slot_token);

  // 3. weight transpose+cast  (w1: [HS][FFN] -> [FFN][HS];  w2: [FFN][HS] -> [HS][FFN])
  transpose_cast_kernel<HS, FFN><<<dim3(FFN / 64, HS / 64, NE), 256, 0, stream>>>(w1, W1t);
  transpose_cast_kernel<FFN, HS><<<dim3(HS / 64, FFN / 64, NE), 256, 0, stream>>>(w2, W2t);

  // 4. gather tokens into expert bins (bf16)
  gather_kernel<<<NE * CAP, 256, 0, stream>>>(x, slot_token, Xg);

  // 5. H = gelu(Xg @ w1)   (M=CAP per expert, N=FFN, K=HS)  MT=16, NT=32
  gemm_bt_kernel<1, 16, 32><<<NE * 16 * 32, 256, 0, stream>>>(Xg, W1t, H, FFN, HS);

  // 6. Out = H @ w2        (M=CAP per expert, N=HS, K=FFN)  MT=16, NT=8
  gemm_bt_kernel<0, 16, 8><<<NE * 16 * 8, 256, 0, stream>>>(H, W2t, Out, HS, FFN);

  // 7. combine back to tokens
  combine_kernel<<<NT, 256, 0, stream>>>(Out, te, asg_p, asg_w, bias, y);
}